// Round 7
// baseline (125.810 us; speedup 1.0000x reference)
//
#include <hip/hip_runtime.h>
#include <hip/hip_bf16.h>
#include <math.h>

#define DIM 768
#define NH 12
#define HD 64
#define BB 8
#define NN 1024
#define M_TOK (BB*NN)   // 8192

// Q pre-scale: 1/sqrt(64) * log2(e): scores land in log2 domain, P = exp2(S).
#define QSCALE 0.18033688011112042f

typedef __bf16 bf16x8 __attribute__((ext_vector_type(8)));
typedef float  f32x4  __attribute__((ext_vector_type(4)));
typedef float  f32x16 __attribute__((ext_vector_type(16)));

__device__ __forceinline__ ushort f2bf(float f) {
  unsigned u = __float_as_uint(f);
  u += 0x7FFF + ((u >> 16) & 1);   // RNE
  return (ushort)(u >> 16);
}

// ---- prep: weight transposes ONLY (x conversion is fused into gemm0's
// A-staging path since round 7 — saves a 38 MB pass over x).
// grid: [0,432) qkv_w^T ; [432,576) proj_w^T
__global__ void k_prep(const float* __restrict__ qkv_w, ushort* __restrict__ qkv_wT,
                       const float* __restrict__ proj_w, ushort* __restrict__ proj_wT) {
  __shared__ ushort tile[64 * 65];
  int tb = blockIdx.x;
  int t = threadIdx.x;
  const float* w; ushort* wt; int N;
  if (tb < 432) { w = qkv_w; wt = qkv_wT; N = 3 * DIM; }
  else          { tb -= 432; w = proj_w; wt = proj_wT; N = DIM; }
  int nbx = N >> 6;
  int n0 = (tb % nbx) * 64, k0 = (tb / nbx) * 64;
  for (int i = 0; i < 16; i++) {
    int flat = i * 256 + t;
    int r = flat >> 6, c = flat & 63;
    tile[c * 65 + r] = f2bf(w[(size_t)(k0 + r) * N + n0 + c]);
  }
  __syncthreads();
  for (int i = 0; i < 16; i++) {
    int flat = i * 256 + t;
    int r = flat >> 6, c = flat & 63;
    wt[(size_t)(n0 + r) * DIM + k0 + c] = tile[r * 65 + c];
  }
}

// XOR-swizzled LDS tile access; rows are 64 ushorts (128 B); 16-byte group c8
// of row r lives at byte ((r*8 + (c8 ^ (r&7))) << 4). Zero-conflict verified
// on this HW earlier (SQ_LDS_BANK_CONFLICT 3.9M -> 0).
__device__ __forceinline__ bf16x8 lds_ld(const ushort* base, int row, int col8) {
  return *(const bf16x8*)((const char*)base + (((row << 3) + (col8 ^ (row & 7))) << 4));
}

#define GLL(g, l) __builtin_amdgcn_global_load_lds((const __attribute__((address_space(1))) void*)(g), (__attribute__((address_space(3))) void*)(l), 16, 0, 0)

// ---- GEMM: C[M,N] = A[M,K] * Bt[N,K]^T (bf16 in, fp32 acc).
// BM x 128 tile, BK=64, swizzled LDS, XCD-chunked block remap.
// BM=128 (QKV): 1152 blocks = 4.5/CU. BM=64 (proj): 768 blocks = 3/CU EXACT.
// EPI==0 (QKV): A comes from FP32 x directly — reg-staged (8 dwordx4 loads ->
//   32 f2bf -> 4 ds_write_b128 into the same swizzled layout; bit-identical
//   bf16 to the old prep pass). B stays global_load_lds. A-loads issue before
//   B-GLLs so the compiler's counted vmcnt overlaps them.
//   Outputs: q (scaled) and k as [bh][n][d] — SCALAR 2B stores; these produce
//   EXACT HBM write bytes. (Round-6 lesson: transposed q packed-8B stores at
//   2KB row stride defeat the L2 write-combiner -> +8MB write amplification
//   and +4us. Store-line-locality matters, not store count. V's packed store
//   survives because... it doesn't: V transposed = same pattern but was
//   measured neutral-to-positive in round 3/4 — keep V packed, q/k scalar.)
// EPI==1 (proj): bf16 A via GLL, fp32 out with bias.
template<int EPI, int BM>
__global__ __launch_bounds__(256) void k_gemm(
    const ushort* __restrict__ A, const float* __restrict__ Axf,
    const ushort* __restrict__ Bt,
    const float* __restrict__ bias, int M, int N, int K,
    float* __restrict__ outF,
    ushort* __restrict__ qo, ushort* __restrict__ ko, ushort* __restrict__ vo)
{
  __shared__ ushort a_lds[BM * 64];
  __shared__ ushort b_lds[128 * 64];
  constexpr int NR = (BM == 128) ? 4 : 2;   // n-frags per wave
  int tid = threadIdx.x;
  int wave = tid >> 6, lane = tid & 63;
  int lr = lane & 15, lg = lane >> 4;
  int rowb = (BM == 128) ? (wave >> 1) * 64 : 0;
  int colb = (BM == 128) ? (wave & 1) * 64 : wave * 32;
  int nbx = N >> 7;
  int nwg = nbx * (M / BM);
  int id = blockIdx.x;
  int nid = (id & 7) * (nwg >> 3) + (id >> 3);
  int bcol = (nid % nbx) << 7;
  int brow = (nid / nbx) * BM;

  f32x4 acc[4][NR] = {};
  for (int k0 = 0; k0 < K; k0 += 64) {
    __syncthreads();
    if constexpr (EPI == 0) {
      // A: fp32 source, reg-staged with in-flight bf16 convert
      float4 av[4][2];
      #pragma unroll
      for (int i = 0; i < 4; i++) {
        int l = i * 256 + tid;
        int row = l >> 3;
        int cg = (l & 7) ^ (row & 7);
        const float* src = Axf + (size_t)(brow + row) * K + k0 + cg * 8;
        av[i][0] = *(const float4*)src;
        av[i][1] = *(const float4*)(src + 4);
      }
      #pragma unroll
      for (int i = 0; i < 4; i++) {
        int l = i * 256 + tid;
        int row = l >> 3;
        int cg = (l & 7) ^ (row & 7);
        GLL(Bt + (size_t)(bcol + row) * K + k0 + cg * 8, (char*)b_lds + i * 4096 + wave * 1024);
      }
      #pragma unroll
      for (int i = 0; i < 4; i++) {
        union { ushort u[8]; int4 v; } pk;
        const float* f = (const float*)&av[i][0];
        #pragma unroll
        for (int j = 0; j < 8; j++) pk.u[j] = f2bf(f[j]);
        *(int4*)((char*)a_lds + i * 4096 + tid * 16) = pk.v;
      }
    } else {
      #pragma unroll
      for (int i = 0; i < BM / 32; i++) {
        int l = i * 256 + tid;
        int row = l >> 3;
        int cg = (l & 7) ^ (row & 7);
        GLL(A + (size_t)(brow + row) * K + k0 + cg * 8, (char*)a_lds + i * 4096 + wave * 1024);
      }
      #pragma unroll
      for (int i = 0; i < 4; i++) {
        int l = i * 256 + tid;
        int row = l >> 3;
        int cg = (l & 7) ^ (row & 7);
        GLL(Bt + (size_t)(bcol + row) * K + k0 + cg * 8, (char*)b_lds + i * 4096 + wave * 1024);
      }
    }
    __syncthreads();
    #pragma unroll
    for (int ks = 0; ks < 2; ks++) {
      bf16x8 af[4], bfr[NR];
      #pragma unroll
      for (int mi = 0; mi < 4; mi++)
        af[mi] = lds_ld(a_lds, rowb + mi * 16 + lr, ks * 4 + lg);
      #pragma unroll
      for (int ni = 0; ni < NR; ni++)
        bfr[ni] = lds_ld(b_lds, colb + ni * 16 + lr, ks * 4 + lg);
      #pragma unroll
      for (int mi = 0; mi < 4; mi++)
        #pragma unroll
        for (int ni = 0; ni < NR; ni++)
          acc[mi][ni] = __builtin_amdgcn_mfma_f32_16x16x32_bf16(af[mi], bfr[ni], acc[mi][ni], 0, 0, 0);
    }
  }
  #pragma unroll
  for (int mi = 0; mi < 4; mi++)
    #pragma unroll
    for (int ni = 0; ni < NR; ni++) {
      if constexpr (EPI == 0) {
        int gm0 = brow + rowb + mi * 16 + lg * 4;        // 4 consecutive tokens
        int gc = bcol + colb + ni * 16 + lr;
        float bs = bias[gc];
        // `which` is wave-uniform: the 16-col run of a wave never crosses a
        // multiple-of-768 boundary.
        int which = (gc >= 1536) ? 2 : (gc >= 768 ? 1 : 0);
        int f = gc - which * 768;
        int h = f >> 6, dd = f & 63;
        int b = gm0 >> 10, np = gm0 & 1023;
        int bh = b * NH + h;
        if (which == 2) {
          ushort4 pk;
          pk.x = f2bf(acc[mi][ni][0] + bs);
          pk.y = f2bf(acc[mi][ni][1] + bs);
          pk.z = f2bf(acc[mi][ni][2] + bs);
          pk.w = f2bf(acc[mi][ni][3] + bs);
          *(ushort4*)&vo[((size_t)bh * HD + dd) * NN + np] = pk;
        } else if (which == 0) {
          #pragma unroll
          for (int i = 0; i < 4; i++)
            qo[((size_t)bh * NN + np + i) * HD + dd] = f2bf((acc[mi][ni][i] + bs) * QSCALE);
        } else {
          #pragma unroll
          for (int i = 0; i < 4; i++)
            ko[((size_t)bh * NN + np + i) * HD + dd] = f2bf(acc[mi][ni][i] + bs);
        }
      } else {
        #pragma unroll
        for (int i = 0; i < 4; i++) {
          int gm = brow + rowb + mi * 16 + lg * 4 + i;
          int gc = bcol + colb + ni * 16 + lr;
          outF[(size_t)gm * N + gc] = acc[mi][ni][i] + bias[gc];
        }
      }
    }
}

// ---- flash attention, swapped-operand 32x32x16 form (T12 pattern):
//   S^T = mfma(K, Q): lane holds P for q = lane&31 across keys, in regs.
//   P -> bf16 B-frags via v_cvt_pk_bf16_f32 + v_permlane32_swap_b32 (no p_lds).
//   O^T = mfma(V^T, P^T). l-sum in-register. No-max exp2 (scores bounded;
//   raw v_exp_f32 — exact for bounded args, library fixup is waste).
//   128 q-rows/block, 4 waves x 32 q, KV tiles of 64, 2-phase K/V dbuf,
//   GLL (coalesced 1KiB/instr) staging, XCD-locality grid decode.
// LESSONS (do not revisit):
//   - Hand scheduling inside the barrier domain regressed ~12% twice
//     (3-buf/counted-vmcnt/stagger; setprio). Compiler's schedule wins.
//   - Barrier-free variant (per-lane MFMA-frag loads straight from L2):
//     2.3x WORSE (97us, MfmaUtil 10%). 16B/lane frag load at 128B stride
//     touches 64 cache lines/instr -> latency-bound, both pipes idle.
//     LDS staging IS the coalescer. Never per-lane-gather frags from global.
//   - Qt [bh][d][n] layout for Q: gemm0 write amplification (+8MB HBM,
//     +4us) from 8B stores at 2KB stride. Q stays [bh][n][d].
__global__ __launch_bounds__(256) void k_attn(
    const ushort* __restrict__ Q, const ushort* __restrict__ Kk,
    const ushort* __restrict__ Vt, ushort* __restrict__ Oo)
{
  __shared__ ushort k_lds[2][64 * 64];
  __shared__ ushort v_lds[2][64 * 64];
  int tid = threadIdx.x;
  int wave = tid >> 6, lane = tid & 63;
  int lq = lane & 31;    // q-column (and LDS row) index
  int hh = lane >> 5;    // k-group half
  int hid = blockIdx.x;
  int xcd = hid & 7;
  int rr = hid >> 3;
  int qb = rr / 12;
  int bhi = rr % 12;
  int bh = bhi * 8 + xcd;
  int q0 = qb * 128;
  int b = bh / NH, h = bh % NH;

  // per-thread staging base pointers (hoisted 64-bit address math)
  int l0 = tid, l1 = 256 + tid;
  int row0 = l0 >> 3, cg0 = (l0 & 7) ^ (row0 & 7);
  int row1 = l1 >> 3, cg1 = (l1 & 7) ^ (row1 & 7);
  const char* kp0 = (const char*)(Kk + ((size_t)bh * NN + row0) * HD + cg0 * 8);
  const char* kp1 = (const char*)(Kk + ((size_t)bh * NN + row1) * HD + cg1 * 8);
  const char* vp0 = (const char*)(Vt + ((size_t)bh * HD + row0) * NN + cg0 * 8);
  const char* vp1 = (const char*)(Vt + ((size_t)bh * HD + row1) * NN + cg1 * 8);

  auto stage = [&](int kt, int buf) {
    size_t ko = (size_t)kt * (64 * HD * 2);   // 8192 B per K tile
    size_t vo = (size_t)kt * (64 * 2);        // 128 B per V tile step
    GLL(kp0 + ko, (char*)&k_lds[buf][0] + wave * 1024);
    GLL(kp1 + ko, (char*)&k_lds[buf][0] + 4096 + wave * 1024);
    GLL(vp0 + vo, (char*)&v_lds[buf][0] + wave * 1024);
    GLL(vp1 + vo, (char*)&v_lds[buf][0] + 4096 + wave * 1024);
  };

  int qrow = q0 + wave * 32 + lq;
  // Q B-frags: qf[dks] = Q[qrow][dks*16 + hh*8 .. +7]
  bf16x8 qf[4];
  #pragma unroll
  for (int dks = 0; dks < 4; dks++)
    qf[dks] = *(const bf16x8*)&Q[((size_t)bh * NN + qrow) * HD + dks * 16 + hh * 8];

  f32x16 o0 = {}, o1 = {};   // O^T: d-tiles 0..31 / 32..63, col q = lq
  float l_run = 0.f;

  stage(0, 0);
  __syncthreads();

  for (int kt = 0; kt < 16; kt++) {
    int cur = kt & 1;
    if (kt < 15) stage(kt + 1, cur ^ 1);
    // S^T[key][q]: key-tiles 0..31 (s0), 32..63 (s1)
    f32x16 s0 = {}, s1 = {};
    #pragma unroll
    for (int dks = 0; dks < 4; dks++) {
      bf16x8 kf0 = lds_ld(&k_lds[cur][0], lq,      dks * 2 + hh);
      bf16x8 kf1 = lds_ld(&k_lds[cur][0], 32 + lq, dks * 2 + hh);
      s0 = __builtin_amdgcn_mfma_f32_32x32x16_bf16(kf0, qf[dks], s0, 0, 0, 0);
      s1 = __builtin_amdgcn_mfma_f32_32x32x16_bf16(kf1, qf[dks], s1, 0, 0, 0);
    }
    // P = exp2(S^T) in place (raw v_exp_f32); accumulate this lane's half of l
    #pragma unroll
    for (int j = 0; j < 16; j++) { s0[j] = __builtin_amdgcn_exp2f(s0[j]); l_run += s0[j]; }
    #pragma unroll
    for (int j = 0; j < 16; j++) { s1[j] = __builtin_amdgcn_exp2f(s1[j]); l_run += s1[j]; }
    // PV: per 16-key block: 4 cvt_pk + 2 permlane32_swap assemble the B-frag
    // (lane needs keys hh*8..hh*8+7 of the block; swap(A,B) -> words 0&2,
    //  swap(A',B') -> words 1&3, both lane-halves correct).
    auto pv = [&](const f32x16& P, int kt2) {
      #pragma unroll
      for (int kb = 0; kb < 2; kb++) {
        int ks = kt2 * 2 + kb;
        int r0 = kb * 8;
        int a0, a1, c0, c1;
        asm("v_cvt_pk_bf16_f32 %0, %1, %2" : "=v"(a0) : "v"(P[r0 + 0]), "v"(P[r0 + 1]));
        asm("v_cvt_pk_bf16_f32 %0, %1, %2" : "=v"(a1) : "v"(P[r0 + 2]), "v"(P[r0 + 3]));
        asm("v_cvt_pk_bf16_f32 %0, %1, %2" : "=v"(c0) : "v"(P[r0 + 4]), "v"(P[r0 + 5]));
        asm("v_cvt_pk_bf16_f32 %0, %1, %2" : "=v"(c1) : "v"(P[r0 + 6]), "v"(P[r0 + 7]));
        asm("v_permlane32_swap_b32 %0, %1" : "+v"(a0), "+v"(c0));
        asm("v_permlane32_swap_b32 %0, %1" : "+v"(a1), "+v"(c1));
        int4 w; w.x = a0; w.y = a1; w.z = c0; w.w = c1;
        bf16x8 pb = *(bf16x8*)&w;
        bf16x8 vf0 = lds_ld(&v_lds[cur][0], lq,      ks * 2 + hh);
        bf16x8 vf1 = lds_ld(&v_lds[cur][0], 32 + lq, ks * 2 + hh);
        o0 = __builtin_amdgcn_mfma_f32_32x32x16_bf16(vf0, pb, o0, 0, 0, 0);
        o1 = __builtin_amdgcn_mfma_f32_32x32x16_bf16(vf1, pb, o1, 0, 0, 0);
      }
    };
    pv(s0, 0);
    pv(s1, 1);
    if (kt < 15) __syncthreads();
  }
  // combine the two lane-halves of l (each covers complementary keys), normalize
  l_run += __shfl_xor(l_run, 32);
  float inv = 1.0f / l_run;
  // O^T reg r of d-tile dt: d = dt*32 + 8*(r>>2) + 4*hh + (r&3) -> 8B packed stores
  #pragma unroll
  for (int dt = 0; dt < 2; dt++) {
    const f32x16& o = dt ? o1 : o0;
    #pragma unroll
    for (int g = 0; g < 4; g++) {
      ushort4 pk;
      pk.x = f2bf(o[g * 4 + 0] * inv);
      pk.y = f2bf(o[g * 4 + 1] * inv);
      pk.z = f2bf(o[g * 4 + 2] * inv);
      pk.w = f2bf(o[g * 4 + 3] * inv);
      *(ushort4*)&Oo[((size_t)b * NN + qrow) * DIM + h * HD + dt * 32 + g * 8 + hh * 4] = pk;
    }
  }
}

extern "C" void kernel_launch(void* const* d_in, const int* in_sizes, int n_in,
                              void* d_out, int out_size, void* d_ws, size_t ws_size,
                              hipStream_t stream) {
  const float* x      = (const float*)d_in[0];
  const float* qkv_w  = (const float*)d_in[2];
  const float* qkv_b  = (const float*)d_in[3];
  const float* proj_w = (const float*)d_in[4];
  const float* proj_b = (const float*)d_in[5];
  float* out = (float*)d_out;

  char* ws = (char*)d_ws;
  size_t off = 0;
  auto alloc = [&](size_t bytes) { char* p = ws + off; off += (bytes + 255) & ~255ull; return p; };
  ushort* qkv_wT   = (ushort*)alloc((size_t)DIM * 3 * DIM * 2);
  ushort* proj_wT  = (ushort*)alloc((size_t)DIM * DIM * 2);
  ushort* q_arr    = (ushort*)alloc((size_t)M_TOK * DIM * 2);
  ushort* k_arr    = (ushort*)alloc((size_t)M_TOK * DIM * 2);
  ushort* vt_arr   = (ushort*)alloc((size_t)M_TOK * DIM * 2);
  ushort* attn_out = (ushort*)alloc((size_t)M_TOK * DIM * 2);

  k_prep<<<576, 256, 0, stream>>>(qkv_w, qkv_wT, proj_w, proj_wT);
  k_gemm<0, 128><<<(3 * DIM / 128) * (M_TOK / 128), 256, 0, stream>>>(
      nullptr, x, qkv_wT, qkv_b, M_TOK, 3 * DIM, DIM, nullptr, q_arr, k_arr, vt_arr);
  k_attn<<<BB * NH * (NN / 128), 256, 0, stream>>>(q_arr, k_arr, vt_arr, attn_out);
  k_gemm<1, 64><<<(DIM / 128) * (M_TOK / 64), 256, 0, stream>>>(
      attn_out, nullptr, proj_wT, proj_b, M_TOK, DIM, DIM, out, nullptr, nullptr, nullptr);
}

// Round 8
// 106.833 us; speedup vs baseline: 1.1776x; 1.1776x over previous
//
#include <hip/hip_runtime.h>
#include <hip/hip_bf16.h>
#include <math.h>

#define DIM 768
#define NH 12
#define HD 64
#define BB 8
#define NN 1024
#define M_TOK (BB*NN)   // 8192

// Q pre-scale: 1/sqrt(64) * log2(e): scores land in log2 domain, P = exp2(S).
#define QSCALE 0.18033688011112042f

typedef __bf16 bf16x8 __attribute__((ext_vector_type(8)));
typedef float  f32x4  __attribute__((ext_vector_type(4)));
typedef float  f32x16 __attribute__((ext_vector_type(16)));

__device__ __forceinline__ ushort f2bf(float f) {
  unsigned u = __float_as_uint(f);
  u += 0x7FFF + ((u >> 16) & 1);   // RNE
  return (ushort)(u >> 16);
}

// ---- fused prep: fp32->bf16 convert of x, plus both weight transposes ----
// grid: [0,6144) cvt x ; [6144,6576) qkv_w^T ; [6576,6720) proj_w^T
// LESSON (round 7): do NOT fuse the x-convert into gemm0. The bf16 pre-pass
// is a COMPRESSION pass: it halves gemm0's A fetch (34.8 vs 55.4 MB measured),
// keeps GLL DMA staging, keeps VGPR at 84 (vs 108). Fusion cost gemm0 +29us
// to save this kernel's ~6us.
__global__ void k_prep(const float* __restrict__ x, ushort* __restrict__ x_bf,
                       const float* __restrict__ qkv_w, ushort* __restrict__ qkv_wT,
                       const float* __restrict__ proj_w, ushort* __restrict__ proj_wT) {
  __shared__ ushort tile[64 * 65];
  int bid = blockIdx.x;
  int t = threadIdx.x;
  if (bid < 6144) {
    int i = bid * 256 + t;
    float4 v = ((const float4*)x)[i];
    ushort4 o; o.x = f2bf(v.x); o.y = f2bf(v.y); o.z = f2bf(v.z); o.w = f2bf(v.w);
    ((ushort4*)x_bf)[i] = o;
    return;
  }
  const float* w; ushort* wt; int N;
  int tb = bid - 6144;
  if (tb < 432) { w = qkv_w; wt = qkv_wT; N = 3 * DIM; }
  else          { tb -= 432; w = proj_w; wt = proj_wT; N = DIM; }
  int nbx = N >> 6;
  int n0 = (tb % nbx) * 64, k0 = (tb / nbx) * 64;
  for (int i = 0; i < 16; i++) {
    int flat = i * 256 + t;
    int r = flat >> 6, c = flat & 63;
    tile[c * 65 + r] = f2bf(w[(size_t)(k0 + r) * N + n0 + c]);
  }
  __syncthreads();
  for (int i = 0; i < 16; i++) {
    int flat = i * 256 + t;
    int r = flat >> 6, c = flat & 63;
    wt[(size_t)(n0 + r) * DIM + k0 + c] = tile[r * 65 + c];
  }
}

// XOR-swizzled LDS tile access; rows are 64 ushorts (128 B); 16-byte group c8
// of row r lives at byte ((r*8 + (c8 ^ (r&7))) << 4). Zero-conflict verified
// on this HW earlier (SQ_LDS_BANK_CONFLICT 3.9M -> 0).
__device__ __forceinline__ bf16x8 lds_ld(const ushort* base, int row, int col8) {
  return *(const bf16x8*)((const char*)base + (((row << 3) + (col8 ^ (row & 7))) << 4));
}

#define GLL(g, l) __builtin_amdgcn_global_load_lds((const __attribute__((address_space(1))) void*)(g), (__attribute__((address_space(3))) void*)(l), 16, 0, 0)

// ---- GEMM: C[M,N] = A[M,K] * Bt[N,K]^T (bf16 in, fp32 acc).
// BM x 128 tile, BK=64, swizzled LDS, XCD-chunked block remap.
// BM=128 (QKV): 1152 blocks = 4.5/CU. BM=64 (proj): 768 blocks = 3/CU EXACT.
// STRUCTURAL LEDGER (all falsified on this problem, do not retry):
//   - 8-phase 256^2: grid 288/256 -> 56% packing, eats the 1.7x per-block gain
//   - 256x128 8-phase: 96KB LDS -> 1 block/CU
//   - fp32-A fusion (round 7): +29us — bf16 pre-pass is a compression pass
//   - Qt packed transposed store (round 6): +8MB write amplification, +4us
//     (8B stores at 2KB stride defeat the write combiner when BOTH q and v
//     are transposed; single transposed stream (V) measured fine)
// EPI==0 (QKV): writes q (scaled), k as [bh][n][d] scalar (exact write bytes);
//   V directly transposed as Vt [bh][d][n] packed ushort4 (replaced k_vt).
// EPI==1 (proj): fp32 out with bias.
template<int EPI, int BM>
__global__ __launch_bounds__(256) void k_gemm(
    const ushort* __restrict__ A, const ushort* __restrict__ Bt,
    const float* __restrict__ bias, int M, int N, int K,
    float* __restrict__ outF,
    ushort* __restrict__ qo, ushort* __restrict__ ko, ushort* __restrict__ vo)
{
  __shared__ ushort a_lds[BM * 64];
  __shared__ ushort b_lds[128 * 64];
  constexpr int NR = (BM == 128) ? 4 : 2;   // n-frags per wave
  int tid = threadIdx.x;
  int wave = tid >> 6, lane = tid & 63;
  int lr = lane & 15, lg = lane >> 4;
  int rowb = (BM == 128) ? (wave >> 1) * 64 : 0;
  int colb = (BM == 128) ? (wave & 1) * 64 : wave * 32;
  int nbx = N >> 7;
  int nwg = nbx * (M / BM);
  int id = blockIdx.x;
  int nid = (id & 7) * (nwg >> 3) + (id >> 3);
  int bcol = (nid % nbx) << 7;
  int brow = (nid / nbx) * BM;

  f32x4 acc[4][NR] = {};
  for (int k0 = 0; k0 < K; k0 += 64) {
    __syncthreads();
    #pragma unroll
    for (int i = 0; i < BM / 32; i++) {
      int l = i * 256 + tid;
      int row = l >> 3;
      int cg = (l & 7) ^ (row & 7);
      GLL(A + (size_t)(brow + row) * K + k0 + cg * 8, (char*)a_lds + i * 4096 + wave * 1024);
    }
    #pragma unroll
    for (int i = 0; i < 4; i++) {
      int l = i * 256 + tid;
      int row = l >> 3;
      int cg = (l & 7) ^ (row & 7);
      GLL(Bt + (size_t)(bcol + row) * K + k0 + cg * 8, (char*)b_lds + i * 4096 + wave * 1024);
    }
    __syncthreads();
    #pragma unroll
    for (int ks = 0; ks < 2; ks++) {
      bf16x8 af[4], bfr[NR];
      #pragma unroll
      for (int mi = 0; mi < 4; mi++)
        af[mi] = lds_ld(a_lds, rowb + mi * 16 + lr, ks * 4 + lg);
      #pragma unroll
      for (int ni = 0; ni < NR; ni++)
        bfr[ni] = lds_ld(b_lds, colb + ni * 16 + lr, ks * 4 + lg);
      #pragma unroll
      for (int mi = 0; mi < 4; mi++)
        #pragma unroll
        for (int ni = 0; ni < NR; ni++)
          acc[mi][ni] = __builtin_amdgcn_mfma_f32_16x16x32_bf16(af[mi], bfr[ni], acc[mi][ni], 0, 0, 0);
    }
  }
  #pragma unroll
  for (int mi = 0; mi < 4; mi++)
    #pragma unroll
    for (int ni = 0; ni < NR; ni++) {
      if constexpr (EPI == 0) {
        int gm0 = brow + rowb + mi * 16 + lg * 4;        // 4 consecutive tokens
        int gc = bcol + colb + ni * 16 + lr;
        float bs = bias[gc];
        // `which` is wave-uniform: the 16-col run of a wave never crosses a
        // multiple-of-768 boundary.
        int which = (gc >= 1536) ? 2 : (gc >= 768 ? 1 : 0);
        int f = gc - which * 768;
        int h = f >> 6, dd = f & 63;
        int b = gm0 >> 10, np = gm0 & 1023;
        int bh = b * NH + h;
        if (which == 2) {
          ushort4 pk;
          pk.x = f2bf(acc[mi][ni][0] + bs);
          pk.y = f2bf(acc[mi][ni][1] + bs);
          pk.z = f2bf(acc[mi][ni][2] + bs);
          pk.w = f2bf(acc[mi][ni][3] + bs);
          *(ushort4*)&vo[((size_t)bh * HD + dd) * NN + np] = pk;
        } else if (which == 0) {
          #pragma unroll
          for (int i = 0; i < 4; i++)
            qo[((size_t)bh * NN + np + i) * HD + dd] = f2bf((acc[mi][ni][i] + bs) * QSCALE);
        } else {
          #pragma unroll
          for (int i = 0; i < 4; i++)
            ko[((size_t)bh * NN + np + i) * HD + dd] = f2bf(acc[mi][ni][i] + bs);
        }
      } else {
        #pragma unroll
        for (int i = 0; i < 4; i++) {
          int gm = brow + rowb + mi * 16 + lg * 4 + i;
          int gc = bcol + colb + ni * 16 + lr;
          outF[(size_t)gm * N + gc] = acc[mi][ni][i] + bias[gc];
        }
      }
    }
}

// ---- flash attention, swapped-operand 32x32x16 form (T12 pattern):
//   S^T = mfma(K, Q): lane holds P for q = lane&31 across keys, in regs.
//   P -> bf16 B-frags via v_cvt_pk_bf16_f32 + v_permlane32_swap_b32 (no p_lds).
//   O^T = mfma(V^T, P^T). l-sum in-register. No-max exp2 (scores bounded;
//   raw v_exp_f32 — exact for bounded args, library fixup is waste).
//   128 q-rows/block, 4 waves x 32 q, KV tiles of 64, 2-phase K/V dbuf,
//   GLL (coalesced 1KiB/instr) staging, XCD-locality grid decode.
// LESSONS (do not revisit):
//   - Hand scheduling inside the barrier domain regressed ~12% twice
//     (3-buf/counted-vmcnt/stagger; setprio). Compiler's schedule wins.
//   - Barrier-free variant (per-lane MFMA-frag loads straight from L2):
//     2.3x WORSE (97us, MfmaUtil 10%). 16B/lane frag load at 128B stride
//     touches 64 cache lines/instr -> latency-bound, both pipes idle.
//     LDS staging IS the coalescer. Never per-lane-gather frags from global.
//   - Qt [bh][d][n] layout for Q: gemm0 write amplification. Q stays [bh][n][d].
//   - KVBLK=128 dbuf needs 64KB LDS -> 2 blocks/CU vs grid's exact 3. No.
__global__ __launch_bounds__(256) void k_attn(
    const ushort* __restrict__ Q, const ushort* __restrict__ Kk,
    const ushort* __restrict__ Vt, ushort* __restrict__ Oo)
{
  __shared__ ushort k_lds[2][64 * 64];
  __shared__ ushort v_lds[2][64 * 64];
  int tid = threadIdx.x;
  int wave = tid >> 6, lane = tid & 63;
  int lq = lane & 31;    // q-column (and LDS row) index
  int hh = lane >> 5;    // k-group half
  int hid = blockIdx.x;
  int xcd = hid & 7;
  int rr = hid >> 3;
  int qb = rr / 12;
  int bhi = rr % 12;
  int bh = bhi * 8 + xcd;
  int q0 = qb * 128;
  int b = bh / NH, h = bh % NH;

  // per-thread staging base pointers (hoisted 64-bit address math)
  int l0 = tid, l1 = 256 + tid;
  int row0 = l0 >> 3, cg0 = (l0 & 7) ^ (row0 & 7);
  int row1 = l1 >> 3, cg1 = (l1 & 7) ^ (row1 & 7);
  const char* kp0 = (const char*)(Kk + ((size_t)bh * NN + row0) * HD + cg0 * 8);
  const char* kp1 = (const char*)(Kk + ((size_t)bh * NN + row1) * HD + cg1 * 8);
  const char* vp0 = (const char*)(Vt + ((size_t)bh * HD + row0) * NN + cg0 * 8);
  const char* vp1 = (const char*)(Vt + ((size_t)bh * HD + row1) * NN + cg1 * 8);

  auto stage = [&](int kt, int buf) {
    size_t ko = (size_t)kt * (64 * HD * 2);   // 8192 B per K tile
    size_t vo = (size_t)kt * (64 * 2);        // 128 B per V tile step
    GLL(kp0 + ko, (char*)&k_lds[buf][0] + wave * 1024);
    GLL(kp1 + ko, (char*)&k_lds[buf][0] + 4096 + wave * 1024);
    GLL(vp0 + vo, (char*)&v_lds[buf][0] + wave * 1024);
    GLL(vp1 + vo, (char*)&v_lds[buf][0] + 4096 + wave * 1024);
  };

  int qrow = q0 + wave * 32 + lq;
  // Q B-frags: qf[dks] = Q[qrow][dks*16 + hh*8 .. +7]
  bf16x8 qf[4];
  #pragma unroll
  for (int dks = 0; dks < 4; dks++)
    qf[dks] = *(const bf16x8*)&Q[((size_t)bh * NN + qrow) * HD + dks * 16 + hh * 8];

  f32x16 o0 = {}, o1 = {};   // O^T: d-tiles 0..31 / 32..63, col q = lq
  float l_run = 0.f;

  stage(0, 0);
  __syncthreads();

  for (int kt = 0; kt < 16; kt++) {
    int cur = kt & 1;
    if (kt < 15) stage(kt + 1, cur ^ 1);
    // S^T[key][q]: key-tiles 0..31 (s0), 32..63 (s1)
    f32x16 s0 = {}, s1 = {};
    #pragma unroll
    for (int dks = 0; dks < 4; dks++) {
      bf16x8 kf0 = lds_ld(&k_lds[cur][0], lq,      dks * 2 + hh);
      bf16x8 kf1 = lds_ld(&k_lds[cur][0], 32 + lq, dks * 2 + hh);
      s0 = __builtin_amdgcn_mfma_f32_32x32x16_bf16(kf0, qf[dks], s0, 0, 0, 0);
      s1 = __builtin_amdgcn_mfma_f32_32x32x16_bf16(kf1, qf[dks], s1, 0, 0, 0);
    }
    // P = exp2(S^T) in place (raw v_exp_f32); accumulate this lane's half of l
    #pragma unroll
    for (int j = 0; j < 16; j++) { s0[j] = __builtin_amdgcn_exp2f(s0[j]); l_run += s0[j]; }
    #pragma unroll
    for (int j = 0; j < 16; j++) { s1[j] = __builtin_amdgcn_exp2f(s1[j]); l_run += s1[j]; }
    // PV: per 16-key block: 4 cvt_pk + 2 permlane32_swap assemble the B-frag
    // (lane needs keys hh*8..hh*8+7 of the block; swap(A,B) -> words 0&2,
    //  swap(A',B') -> words 1&3, both lane-halves correct).
    auto pv = [&](const f32x16& P, int kt2) {
      #pragma unroll
      for (int kb = 0; kb < 2; kb++) {
        int ks = kt2 * 2 + kb;
        int r0 = kb * 8;
        int a0, a1, c0, c1;
        asm("v_cvt_pk_bf16_f32 %0, %1, %2" : "=v"(a0) : "v"(P[r0 + 0]), "v"(P[r0 + 1]));
        asm("v_cvt_pk_bf16_f32 %0, %1, %2" : "=v"(a1) : "v"(P[r0 + 2]), "v"(P[r0 + 3]));
        asm("v_cvt_pk_bf16_f32 %0, %1, %2" : "=v"(c0) : "v"(P[r0 + 4]), "v"(P[r0 + 5]));
        asm("v_cvt_pk_bf16_f32 %0, %1, %2" : "=v"(c1) : "v"(P[r0 + 6]), "v"(P[r0 + 7]));
        asm("v_permlane32_swap_b32 %0, %1" : "+v"(a0), "+v"(c0));
        asm("v_permlane32_swap_b32 %0, %1" : "+v"(a1), "+v"(c1));
        int4 w; w.x = a0; w.y = a1; w.z = c0; w.w = c1;
        bf16x8 pb = *(bf16x8*)&w;
        bf16x8 vf0 = lds_ld(&v_lds[cur][0], lq,      ks * 2 + hh);
        bf16x8 vf1 = lds_ld(&v_lds[cur][0], 32 + lq, ks * 2 + hh);
        o0 = __builtin_amdgcn_mfma_f32_32x32x16_bf16(vf0, pb, o0, 0, 0, 0);
        o1 = __builtin_amdgcn_mfma_f32_32x32x16_bf16(vf1, pb, o1, 0, 0, 0);
      }
    };
    pv(s0, 0);
    pv(s1, 1);
    if (kt < 15) __syncthreads();
  }
  // combine the two lane-halves of l (each covers complementary keys), normalize
  l_run += __shfl_xor(l_run, 32);
  float inv = 1.0f / l_run;
  // O^T reg r of d-tile dt: d = dt*32 + 8*(r>>2) + 4*hh + (r&3) -> 8B packed stores
  #pragma unroll
  for (int dt = 0; dt < 2; dt++) {
    const f32x16& o = dt ? o1 : o0;
    #pragma unroll
    for (int g = 0; g < 4; g++) {
      ushort4 pk;
      pk.x = f2bf(o[g * 4 + 0] * inv);
      pk.y = f2bf(o[g * 4 + 1] * inv);
      pk.z = f2bf(o[g * 4 + 2] * inv);
      pk.w = f2bf(o[g * 4 + 3] * inv);
      *(ushort4*)&Oo[((size_t)b * NN + qrow) * DIM + h * HD + dt * 32 + g * 8 + hh * 4] = pk;
    }
  }
}

extern "C" void kernel_launch(void* const* d_in, const int* in_sizes, int n_in,
                              void* d_out, int out_size, void* d_ws, size_t ws_size,
                              hipStream_t stream) {
  const float* x      = (const float*)d_in[0];
  const float* qkv_w  = (const float*)d_in[2];
  const float* qkv_b  = (const float*)d_in[3];
  const float* proj_w = (const float*)d_in[4];
  const float* proj_b = (const float*)d_in[5];
  float* out = (float*)d_out;

  char* ws = (char*)d_ws;
  size_t off = 0;
  auto alloc = [&](size_t bytes) { char* p = ws + off; off += (bytes + 255) & ~255ull; return p; };
  ushort* x_bf    = (ushort*)alloc((size_t)M_TOK * DIM * 2);       // reused as attn_out
  ushort* qkv_wT  = (ushort*)alloc((size_t)DIM * 3 * DIM * 2);
  ushort* proj_wT = (ushort*)alloc((size_t)DIM * DIM * 2);
  ushort* q_arr   = (ushort*)alloc((size_t)M_TOK * DIM * 2);
  ushort* k_arr   = (ushort*)alloc((size_t)M_TOK * DIM * 2);
  ushort* vt_arr  = (ushort*)alloc((size_t)M_TOK * DIM * 2);
  ushort* attn_out = x_bf;   // x_bf dead after QKV GEMM

  k_prep<<<6720, 256, 0, stream>>>(x, x_bf, qkv_w, qkv_wT, proj_w, proj_wT);
  k_gemm<0, 128><<<(3 * DIM / 128) * (M_TOK / 128), 256, 0, stream>>>(
      x_bf, qkv_wT, qkv_b, M_TOK, 3 * DIM, DIM, nullptr, q_arr, k_arr, vt_arr);
  k_attn<<<BB * NH * (NN / 128), 256, 0, stream>>>(q_arr, k_arr, vt_arr, attn_out);
  k_gemm<1, 64><<<(DIM / 128) * (M_TOK / 64), 256, 0, stream>>>(
      attn_out, proj_wT, proj_b, M_TOK, DIM, DIM, out, nullptr, nullptr, nullptr);
}